// Round 1
// 158.866 us; speedup vs baseline: 1.0052x; 1.0052x over previous
//
#include <hip/hip_runtime.h>

// Problem constants (from reference): B=64, L=512, H=768, W=255
#define B_ 64
#define L_ 512
#define H_ 768
#define W_ 255
#define H4 (H_ / 4)       // 192 float4 per token row
#define WPB 8             // words per block
#define NCHUNK 32         // ceil(W_/WPB); chunk id NCHUNK is the CLS-copy slot

// One fused kernel, batched-load version with single-pass length scan.
// grid = (NCHUNK+1, B), block = 192 threads (3 waves), thread t owns float4 col t.
//
// Prolog rework vs previous version: instead of up to 4 serially-dependent
// {load 64 lengths -> 64-lane scan -> carry} passes, each lane loads 4
// lengths (4 INDEPENDENT scalar loads, one waitcnt), reduces in-lane, and a
// single 64-lane shuffle scan covers all 256 word slots. Because
// w0 = 8*chunk is a multiple of 4, the broadcast source lane (2*chunk+(j>>2))
// and the sub-word index (j&3) are compile-time after unrolling.
//
// Main loop unchanged: words_lengths here are {1,2}; for each of the 8 words
// we unconditionally issue TWO row loads (second = start+1 if len>1, else a
// dup that hits L1). Fully unrolled -> 16 independent global_load_dwordx4 in
// flight per wave. A guarded fallback loop handles len>2 for generality.
__global__ __launch_bounds__(H4) void wordrep_fused(
        const float* __restrict__ seq,
        const int* __restrict__ lengths,
        float* __restrict__ cls_out,
        float* __restrict__ ctx_out) {
    int chunk = blockIdx.x;
    int b     = blockIdx.y;
    int t     = threadIdx.x;          // 0..191
    const float4* base = (const float4*)(seq + (size_t)b * L_ * H_);

    if (chunk == NCHUNK) {
        // cls_output[b,:] = seq[b, 0, :]
        ((float4*)cls_out)[(size_t)b * H4 + t] = base[t];
        return;
    }

    int w0 = chunk * WPB;
    int nw = min(WPB, W_ - w0);       // 8, except last chunk = 7
    int lane = t & 63;
    const int* len = lengths + b * W_;

    // --- single-pass prefix scan of all 255 lengths ---
    // Lane `lane` owns words 4*lane .. 4*lane+3. Row stride (255 ints) is not
    // 16B-aligned, so use 4 independent scalar loads (they coalesce per pair
    // of lanes and all issue back-to-back; only one waitcnt).
    int idx = lane * 4;
    int v0 = len[idx];                               // idx <= 252, always valid
    int v1 = (idx + 1 < W_) ? len[idx + 1] : 0;
    int v2 = (idx + 2 < W_) ? len[idx + 2] : 0;
    int v3 = (idx + 3 < W_) ? len[idx + 3] : 0;

    int lsum = v0 + v1 + v2 + v3;
    int s = lsum;
    #pragma unroll
    for (int off = 1; off < 64; off <<= 1) {
        int u = __shfl_up(s, off, 64);
        if (lane >= off) s += u;
    }
    int p = s - lsum;                 // tokens consumed before this lane's 4 words
    int st0 = 1 + p;                  // word 4*lane starts after CLS token 0
    int st1 = st0 + v0;
    int st2 = st1 + v1;
    int st3 = st2 + v2;

    // Broadcast the 8 (start, len) pairs for words w0..w0+7.
    // They live in lanes 2*chunk and 2*chunk+1 (since w0 % 4 == 0).
    int s_[WPB], l_[WPB];
    #pragma unroll
    for (int j = 0; j < WPB; ++j) {
        int src = 2 * chunk + (j >> 2);   // <= 63
        int sj, lj;
        switch (j & 3) {                  // compile-time after unroll
            case 0:  sj = st0; lj = v0; break;
            case 1:  sj = st1; lj = v1; break;
            case 2:  sj = st2; lj = v2; break;
            default: sj = st3; lj = v3; break;
        }
        s_[j] = __shfl(sj, src, 64);
        l_[j] = __shfl(lj, src, 64);
    }

    // Issue all 16 row loads back-to-back (no intervening waitcnt).
    float4 a0[WPB], a1[WPB];
    #pragma unroll
    for (int j = 0; j < WPB; ++j) {
        int t0 = min(max(s_[j], 0), L_ - 1);                      // clamped-safe
        int t1 = min(max(s_[j] + (l_[j] > 1 ? 1 : 0), 0), L_ - 1);
        a0[j] = base[(size_t)t0 * H4 + t];
        a1[j] = base[(size_t)t1 * H4 + t];
    }

    float4* out = (float4*)ctx_out + ((size_t)b * W_ + w0) * H4 + t;

    #pragma unroll
    for (int j = 0; j < WPB; ++j) {
        int lj = l_[j];
        float m1 = (lj > 1) ? 1.0f : 0.0f;
        float4 acc;
        acc.x = a0[j].x + m1 * a1[j].x;
        acc.y = a0[j].y + m1 * a1[j].y;
        acc.z = a0[j].z + m1 * a1[j].z;
        acc.w = a0[j].w + m1 * a1[j].w;
        if (lj > 2) {                 // generality fallback; never taken here
            int end = min(s_[j] + lj, L_);
            for (int tok = s_[j] + 2; tok < end; ++tok) {
                float4 v = base[(size_t)tok * H4 + t];
                acc.x += v.x; acc.y += v.y; acc.z += v.z; acc.w += v.w;
            }
        }
        float inv = (lj > 0) ? (1.0f / (float)lj) : 0.0f;
        acc.x *= inv; acc.y *= inv; acc.z *= inv; acc.w *= inv;
        if (lj <= 0) { acc.x = 0.f; acc.y = 0.f; acc.z = 0.f; acc.w = 0.f; }
        if (j < nw) out[(size_t)j * H4] = acc;
    }
}

extern "C" void kernel_launch(void* const* d_in, const int* in_sizes, int n_in,
                              void* d_out, int out_size, void* d_ws, size_t ws_size,
                              hipStream_t stream) {
    const float* seq     = (const float*)d_in[0];   // (B, L, H) fp32
    const int*   lengths = (const int*)d_in[1];     // (B, W) int32

    float* cls_out = (float*)d_out;                        // (B, H)
    float* ctx_out = (float*)d_out + (size_t)B_ * H_;      // (B, W, H)

    dim3 grid(NCHUNK + 1, B_);   // 33 x 64 = 2112 blocks
    wordrep_fused<<<grid, H4, 0, stream>>>(seq, lengths, cls_out, ctx_out);
}